// Round 7
// baseline (198.662 us; speedup 1.0000x reference)
//
#include <hip/hip_runtime.h>
#include <hip/hip_bf16.h>

#define BATCH 16384

typedef __attribute__((ext_vector_type(8))) short short8;
typedef __attribute__((ext_vector_type(4))) short short4v;
typedef __attribute__((ext_vector_type(2))) short sshort2;
typedef __attribute__((ext_vector_type(8))) unsigned short ushort8;
typedef __attribute__((ext_vector_type(4))) unsigned short ushort4v;
typedef __attribute__((ext_vector_type(4))) float float4v;

// ---- d_ws layout (bytes) ----
// Per-net CONTIGUOUS frag block (staged whole into LDS):
//   [A1: [th:4][lane:64][32B] = 8192 | A2: [p:2][tg:4][lane:64][16B] = 8192 |
//    A3: [p:2][lane:64][16B] = 2048 | B1: 64 f32 = 256 | B2: 64 f32 = 256]
// A2/A3 laid out for 16x16x32 MFMA with k-slot permutation
//   phi(quad,j) = 32p + ((j>=4)?16:0) + 4*quad + (j&3)
// matching the L1/L2 output fragment (h = 16*th + 4*quad + i) so a th-step PAIR
// feeds one K=32 MFMA with zero shuffles (R5-verified: 112 -> 72 MFMA issues).
#define FR_STRIDE  18944u
#define FR_SIZE    (63u * FR_STRIDE)      // 1193472
#define OFF_A2     8192u
#define OFF_A3     16384u
#define OFF_B1     18432u
#define OFF_B2     18688u
#define XBF_SIZE   2097152u     // x as bf16 [16384][64]
#define FR_ELEMS   1184         // FR_STRIDE / 16

__device__ __forceinline__ unsigned int packbf2(float a, float b) {
#if __has_builtin(__builtin_amdgcn_cvt_pk_bf16_f32)
    typedef __attribute__((ext_vector_type(2))) __bf16 bf2_t;
    union { bf2_t h; unsigned int u; } v;
    v.h = __builtin_amdgcn_cvt_pk_bf16_f32(a, b);
    return v.u;
#else
    union { __hip_bfloat162 h; unsigned int u; } v;
    v.h = __float22bfloat162_rn(make_float2(a, b));
    return v.u;
#endif
}
// packed relu on two bf16 halves: i16 max with 0 (valid: bf16 neg <=> i16 neg; no NaNs here)
__device__ __forceinline__ unsigned int relu_pk(unsigned int u) {
#if __has_builtin(__builtin_elementwise_max)
    union { sshort2 s; unsigned int w; } v; v.w = u;
    v.s = __builtin_elementwise_max(v.s, (sshort2)0);
    return v.w;
#else
    unsigned int lo = (u & 0x8000u) ? 0u : (u & 0xFFFFu);
    unsigned int hi = (u & 0x80000000u) ? 0u : (u & 0xFFFF0000u);
    return lo | hi;
#endif
}
__device__ __forceinline__ unsigned int cvt_relu(float a, float b) {
    return relu_pk(packbf2(a, b));
}
__device__ __forceinline__ unsigned short f2bf(float a) {
    union { __hip_bfloat16 h; unsigned short u; } v;
    v.h = __float2bfloat16(a);
    return v.u;
}

// async 16B global -> LDS DMA (wave-uniform LDS base + lane*16 by construction)
__device__ __forceinline__ void gl_lds16(const char* gsrc, char* ldst) {
    __builtin_amdgcn_global_load_lds(
        (const __attribute__((address_space(1))) unsigned int*)gsrc,
        (__attribute__((address_space(3))) unsigned int*)ldst,
        16, 0, 0);
}

// ---------------- setup: fused weight-fragment prep (blocks 0..62) + x cvt (blocks 63..318) ----------------
__global__ __launch_bounds__(256) void setup_kernel(
    const float* __restrict__ x,
    const float* __restrict__ W1,  // [63,64,64] [d][h]
    const float* __restrict__ W2,  // [63,64,64] [h][g]
    const float* __restrict__ W3,  // [63,64,2]  [g][o]
    const float* __restrict__ B1,  // [63,64]
    const float* __restrict__ B2,  // [63,64]
    char* __restrict__ frag,
    char* __restrict__ xbf)        // may be null when grid==63
{
    const int b = blockIdx.x;
    const int t = threadIdx.x;

    if (b >= 63) {
        const int idx = (b - 63) * 256 + t;          // 0..65535, 16 floats each
        const float* xp = x + (size_t)idx * 16;
        char* dst = xbf + (size_t)idx * 32;
        #pragma unroll
        for (int h = 0; h < 2; ++h) {
            float4v f0 = *(const float4v*)(xp + h * 8);
            float4v f1 = *(const float4v*)(xp + h * 8 + 4);
            union { ushort8 s; unsigned int u[4]; } p;
            p.u[0] = packbf2(f0[0], f0[1]);
            p.u[1] = packbf2(f0[2], f0[3]);
            p.u[2] = packbf2(f1[0], f1[1]);
            p.u[3] = packbf2(f1[2], f1[3]);
            *(ushort8*)(dst + h * 16) = p.s;
        }
        return;
    }

    __shared__ float sW1[4096];   // 16 KB
    __shared__ float sW2[4096];   // 16 KB

    const int kn   = b;
    const int net  = kn + 1;
    const int lane = t & 63;
    const int grp  = t >> 6;       // th (A1) / p (A3)
    const int lq   = lane & 15;
    const int quad = lane >> 4;

    // coalesced stage: 4 float4 per thread per matrix
    {
        const float4v* s1 = (const float4v*)(W1 + kn * 4096);
        const float4v* s2 = (const float4v*)(W2 + kn * 4096);
        #pragma unroll
        for (int i = 0; i < 4; ++i) {
            ((float4v*)sW1)[i * 256 + t] = s1[i * 256 + t];
            ((float4v*)sW2)[i * 256 + t] = s2[i * 256 + t];
        }
    }
    __syncthreads();

    char* base = frag + (size_t)kn * FR_STRIDE;

    // A1: A[m=h=lq+16*th][k=d=quad*8+j (a10) / +32 (a11)], masked d < net
    {
        const int h = lq + 16 * grp;
        ushort8 a10, a11;
        #pragma unroll
        for (int j = 0; j < 8; ++j) {
            const int d0 = quad * 8 + j;
            const int d1 = d0 + 32;
            a10[j] = (d0 < net) ? f2bf(sW1[d0 * 64 + h]) : (unsigned short)0;
            a11[j] = (d1 < net) ? f2bf(sW1[d1 * 64 + h]) : (unsigned short)0;
        }
        char* dst = base + grp * 2048 + lane * 32;
        *(ushort8*)(dst)      = a10;
        *(ushort8*)(dst + 16) = a11;
    }

    // A2 (16x16x32): A[m=g=lq+16*tg][k-slot (quad,j)] with h = phi(quad,j)
    // pair p covers h in [32p, 32p+32)
    {
        const int g = lq + 16 * grp;   // grp doubles as tg here
        #pragma unroll
        for (int p = 0; p < 2; ++p) {
            ushort8 v;
            #pragma unroll
            for (int j = 0; j < 8; ++j) {
                const int h = 32 * p + ((j & 4) << 2) + 4 * quad + (j & 3);
                v[j] = f2bf(sW2[h * 64 + g]);
            }
            *(ushort8*)(base + OFF_A2 + p * 4096 + grp * 1024 + lane * 16) = v;
        }
    }

    // A3 (16x16x32): A[m=o=lq (0/1)][k-slot (quad,j)] with g = phi(quad,j); rows >= 2 zero
    if (grp < 2) {
        const int p = grp;
        ushort8 v;
        #pragma unroll
        for (int j = 0; j < 8; ++j) {
            const int gg = 32 * p + ((j & 4) << 2) + 4 * quad + (j & 3);
            v[j] = (lq < 2) ? f2bf(W3[kn * 128 + gg * 2 + lq]) : (unsigned short)0;
        }
        *(ushort8*)(base + OFF_A3 + p * 1024 + lane * 16) = v;
    }

    // B1/B2 raw f32 copies
    if (t < 64) {
        *(float*)(base + OFF_B1 + t * 4) = B1[kn * 64 + t];
        *(float*)(base + OFF_B2 + t * 4) = B2[kn * 64 + t];
    }
}

// ---------------- main: grid 1024 = 64 chunks x 16 groups x 4 nets; 4 blocks/CU ----------------
// R7: occupancy was LDS-bound (52.2KB -> 3 blocks/CU). sOut removed (direct
// exec-masked global stores; partial-line writes merge in L2) -> LDS 37.9KB ->
// 4 blocks/CU. tm-SPLIT body (rows 0-31 then 32-63 through all layers) halves
// acc2 to [4][2] so (256,4)'s 128-reg cap holds WITHOUT spill (old 112-MFMA
// body spilled at this cap; R2's ILP loss doesn't apply now that frags are
// LDS-resident). Grid 1024 = exactly 4/CU, single generation, even groups.
template <bool XBF>
__global__ __launch_bounds__(256, 4) void arnet_main4(
    const float* __restrict__ x,
    const char* __restrict__ xbf,
    const char* __restrict__ frag,
    const float* __restrict__ w0, const float* __restrict__ b0,
    const float* __restrict__ v0, const float* __restrict__ c0,
    const float* __restrict__ B3,
    float* __restrict__ out)
{
    const int bi    = blockIdx.x;        // 0..1023
    const int chunk = bi & 63;           // 256-row chunk
    const int gi    = bi >> 6;           // 0..15
    const int start = gi * 4;
    const int t     = threadIdx.x;

    const int lane = t & 63;
    const int w    = t >> 6;
    const int lq   = lane & 15;
    const int quad = lane >> 4;

    __shared__ __align__(16) char sFrag[2][FR_STRIDE];   // 37888 B double-buffer

    const int rowbase = chunk * 256 + w * 64;

    // ---- load x fragments ONCE (64 rows/wave), reuse for all nets of the group ----
    short8 xf[4][2];
    #pragma unroll
    for (int tm = 0; tm < 4; ++tm) {
        if (XBF) {
            const char* base = xbf + (size_t)(rowbase + 16 * tm + lq) * 128 + quad * 16;
            xf[tm][0] = *(const short8*)(base);
            xf[tm][1] = *(const short8*)(base + 64);
        } else {
            const float* xr = x + (size_t)(rowbase + 16 * tm + lq) * 64 + quad * 8;
            #pragma unroll
            for (int half = 0; half < 2; ++half) {
                float4v f0 = *(const float4v*)(xr + 32 * half);
                float4v f1 = *(const float4v*)(xr + 32 * half + 4);
                union { short8 s; unsigned int u[4]; } p;
                p.u[0] = packbf2(f0[0], f0[1]);
                p.u[1] = packbf2(f0[2], f0[3]);
                p.u[2] = packbf2(f1[0], f1[1]);
                p.u[3] = packbf2(f1[2], f1[3]);
                xf[tm][half] = p.s;
            }
        }
    }

    // ---- async stage of one net's frag block into LDS ----
    auto stage = [&](int net_, char* dstb) {
        const char* src = frag + (size_t)(net_ - 1) * FR_STRIDE;
        #pragma unroll
        for (int i = 0; i < 5; ++i) {
            const int e = i * 256 + t;
            if (e < FR_ELEMS)
                gl_lds16(src + e * 16, dstb + e * 16);
        }
    };

    const int first = (start == 0) ? 1 : 0;  // idx of first MFMA net in this group
    stage(start + first, sFrag[first & 1]);
    __syncthreads();                          // drain vmcnt -> first buffer ready

    #pragma unroll 1
    for (int idx = 0; idx < 4; ++idx) {
        const int net = start + idx;

        // prefetch next net while computing this one (skips the pre-staged first)
        if (idx + 1 < 4 && idx + 1 > first)
            stage(start + idx + 1, sFrag[(idx + 1) & 1]);

        if (net == 0) {
            // constant network: uniform scalar; each thread writes col 0 of its row
            float s = 0.f, tr = 0.f;
            #pragma unroll 8
            for (int j = 0; j < 64; ++j) {
                float h = fmaxf(w0[j] + b0[j], 0.f);
                s  += h * v0[2 * j];
                tr += h * v0[2 * j + 1];
            }
            s += c0[0];
            tr += c0[1];
            s = fminf(fmaxf(s, -5.f), 5.f);
            const size_t grow = (size_t)chunk * 256 + t;
            out[grow * 64] = s;
            out[((size_t)BATCH + grow) * 64] = tr;
            __syncthreads();                  // iteration barrier (drains prefetch)
            continue;
        }

        const int kn = net - 1;
        const char* sf  = sFrag[idx & 1];
        const char* pA1 = sf + lane * 32;
        const char* pA2 = sf + OFF_A2 + lane * 16;
        const char* pA3 = sf + OFF_A3 + lane * 16;
        const float* bB1 = (const float*)(sf + OFF_B1);
        const float* bB2 = (const float*)(sf + OFF_B2);

        const float b30 = B3[kn * 2], b31 = B3[kn * 2 + 1];

        // ---- tm-split body: rows [32*mh, 32*mh+32) through all 3 layers ----
        #pragma unroll 1
        for (int mh = 0; mh < 2; ++mh) {
            float4v acc2[4][2];
            #pragma unroll
            for (int p = 0; p < 2; ++p) {
                unsigned int pk[2][2][2];   // [sub-th][dword][tm]
                #pragma unroll
                for (int s = 0; s < 2; ++s) {
                    const int th = 2 * p + s;
                    short8 a10 = *(const short8*)(pA1 + th * 2048);
                    short8 a11 = *(const short8*)(pA1 + th * 2048 + 16);
                    float4v bias1 = *(const float4v*)(bB1 + quad * 4 + 16 * th);
                    #pragma unroll
                    for (int tm = 0; tm < 2; ++tm) {
                        float4v acc1;
                        acc1 = __builtin_amdgcn_mfma_f32_16x16x32_bf16(a10, xf[2 * mh + tm][0], bias1, 0, 0, 0);
                        acc1 = __builtin_amdgcn_mfma_f32_16x16x32_bf16(a11, xf[2 * mh + tm][1], acc1, 0, 0, 0);
                        pk[s][0][tm] = cvt_relu(acc1[0], acc1[1]);
                        pk[s][1][tm] = cvt_relu(acc1[2], acc1[3]);
                    }
                }
                #pragma unroll
                for (int tg = 0; tg < 4; ++tg) {
                    short8 a2 = *(const short8*)(pA2 + p * 4096 + tg * 1024);
                    float4v bias2 = *(const float4v*)(bB2 + quad * 4 + 16 * tg);
                    #pragma unroll
                    for (int tm = 0; tm < 2; ++tm) {
                        union { short8 s8; unsigned int u[4]; } bb;
                        bb.u[0] = pk[0][0][tm]; bb.u[1] = pk[0][1][tm];
                        bb.u[2] = pk[1][0][tm]; bb.u[3] = pk[1][1][tm];
                        acc2[tg][tm] = __builtin_amdgcn_mfma_f32_16x16x32_bf16(
                            a2, bb.s8, (p == 0) ? bias2 : acc2[tg][tm], 0, 0, 0);
                    }
                }
            }

            // ---- layer 3: paired tg-steps -> K=32 ----
            float4v c3v;
            c3v[0] = b30; c3v[1] = b31; c3v[2] = 0.f; c3v[3] = 0.f;
            float4v acc3[2];
            #pragma unroll
            for (int p = 0; p < 2; ++p) {
                short8 a3 = *(const short8*)(pA3 + p * 1024);
                #pragma unroll
                for (int tm = 0; tm < 2; ++tm) {
                    union { short8 s8; unsigned int u[4]; } bb;
                    bb.u[0] = cvt_relu(acc2[2 * p][tm][0],     acc2[2 * p][tm][1]);
                    bb.u[1] = cvt_relu(acc2[2 * p][tm][2],     acc2[2 * p][tm][3]);
                    bb.u[2] = cvt_relu(acc2[2 * p + 1][tm][0], acc2[2 * p + 1][tm][1]);
                    bb.u[3] = cvt_relu(acc2[2 * p + 1][tm][2], acc2[2 * p + 1][tm][3]);
                    acc3[tm] = __builtin_amdgcn_mfma_f32_16x16x32_bf16(
                        a3, bb.s8, (p == 0) ? c3v : acc3[tm], 0, 0, 0);
                }
            }

            // ---- direct write-out (quad0 lanes hold rows; partial lines merge in L2) ----
            if (quad == 0) {
                #pragma unroll
                for (int tm = 0; tm < 2; ++tm) {
                    const size_t grow = (size_t)rowbase + 16 * (2 * mh + tm) + lq;
                    out[grow * 64 + net] = fminf(fmaxf(acc3[tm][0], -5.f), 5.f);
                    out[((size_t)BATCH + grow) * 64 + net] = acc3[tm][1];
                }
            }
        }

        __syncthreads();                      // drains prefetch DMA + orders dbuf reuse
    }
}

// ---------------- fallback (verified): used only if ws_size < FR_SIZE ----------------
#define WPAD 72
__global__ __launch_bounds__(256) void arnet_fallback(
    const float* __restrict__ x, const float* __restrict__ w0, const float* __restrict__ b0,
    const float* __restrict__ v0, const float* __restrict__ c0,
    const float* __restrict__ W1, const float* __restrict__ B1,
    const float* __restrict__ W2, const float* __restrict__ B2,
    const float* __restrict__ W3, const float* __restrict__ B3,
    float* __restrict__ out)
{
    const int bi = blockIdx.x;
    const int net = bi >> 5;
    const int tile = bi & 31;
    const int t = threadIdx.x;
    if (net == 0) {
        float s = 0.f, tr = 0.f;
        for (int j = 0; j < 64; ++j) {
            float h = fmaxf(w0[j] + b0[j], 0.f);
            s += h * v0[2 * j]; tr += h * v0[2 * j + 1];
        }
        s += c0[0]; tr += c0[1];
        s = fminf(fmaxf(s, -5.f), 5.f);
        const size_t r0 = (size_t)tile * 512;
        out[(r0 + t) * 64] = s; out[(size_t)BATCH * 64 + (r0 + t) * 64] = tr;
        out[(r0 + 256 + t) * 64] = s; out[(size_t)BATCH * 64 + (r0 + 256 + t) * 64] = tr;
        return;
    }
    __shared__ unsigned short sW1T[64 * WPAD];
    __shared__ unsigned short sW2T[64 * WPAD];
    __shared__ unsigned short sW3T[2 * 64];
    __shared__ float sB1[64];
    __shared__ float sB2[64];
    const int kn = net - 1;
    {
        const int hb = (t & 15) * 4, jb = (t >> 4) * 4;
        const float* src1 = W1 + kn * 4096;
        const float* src2 = W2 + kn * 4096;
        float4v a[4], b[4];
        for (int jj = 0; jj < 4; ++jj) {
            a[jj] = *(const float4v*)(src1 + (jb + jj) * 64 + hb);
            if (jb + jj >= net) a[jj] = (float4v)0.f;
            b[jj] = *(const float4v*)(src2 + (jb + jj) * 64 + hb);
        }
        for (int hh = 0; hh < 4; ++hh) {
            ushort4v ra, rb;
            for (int jj = 0; jj < 4; ++jj) { ra[jj] = f2bf(a[jj][hh]); rb[jj] = f2bf(b[jj][hh]); }
            *(ushort4v*)(&sW1T[(hb + hh) * WPAD + jb]) = ra;
            *(ushort4v*)(&sW2T[(hb + hh) * WPAD + jb]) = rb;
        }
    }
    if (t < 64) {
        sW3T[t] = f2bf(W3[kn * 128 + t * 2]);
        sW3T[64 + t] = f2bf(W3[kn * 128 + t * 2 + 1]);
        sB1[t] = B1[kn * 64 + t];
        sB2[t] = B2[kn * 64 + t];
    }
    const float b30 = B3[kn * 2], b31 = B3[kn * 2 + 1];
    __syncthreads();
    const int lane = t & 63, w = t >> 6, lq = lane & 15, quad = lane >> 4;
    for (int pass = 0; pass < 2; ++pass) {
        const int rowbase = tile * 512 + pass * 256 + w * 64;
        short8 xf[4][2];
        for (int tm = 0; tm < 4; ++tm) {
            const float* xr = x + (size_t)(rowbase + 16 * tm + lq) * 64 + quad * 8;
            for (int half = 0; half < 2; ++half) {
                float4v f0 = *(const float4v*)(xr + 32 * half);
                float4v f1 = *(const float4v*)(xr + 32 * half + 4);
                union { short8 s; unsigned int u[4]; } p;
                p.u[0] = packbf2(f0[0], f0[1]); p.u[1] = packbf2(f0[2], f0[3]);
                p.u[2] = packbf2(f1[0], f1[1]); p.u[3] = packbf2(f1[2], f1[3]);
                xf[tm][half] = p.s;
            }
        }
        float4v acc2[4][4];
        for (int tg = 0; tg < 4; ++tg) {
            float4v bias2 = *(const float4v*)(&sB2[quad * 4 + 16 * tg]);
            for (int tm = 0; tm < 4; ++tm) acc2[tg][tm] = bias2;
        }
        for (int th = 0; th < 4; ++th) {
            float4v bias1 = *(const float4v*)(&sB1[quad * 4 + 16 * th]);
            short8 a10 = *(const short8*)(&sW1T[(lq + 16 * th) * WPAD + quad * 8]);
            short8 a11 = *(const short8*)(&sW1T[(lq + 16 * th) * WPAD + quad * 8 + 32]);
            float4v acc1[4];
            for (int tm = 0; tm < 4; ++tm) {
                acc1[tm] = bias1;
                acc1[tm] = __builtin_amdgcn_mfma_f32_16x16x32_bf16(a10, xf[tm][0], acc1[tm], 0, 0, 0);
                acc1[tm] = __builtin_amdgcn_mfma_f32_16x16x32_bf16(a11, xf[tm][1], acc1[tm], 0, 0, 0);
            }
            short4v bf1[4];
            for (int tm = 0; tm < 4; ++tm) {
                union { short4v s; unsigned int u[2]; } pk;
                pk.u[0] = cvt_relu(acc1[tm][0], acc1[tm][1]);
                pk.u[1] = cvt_relu(acc1[tm][2], acc1[tm][3]);
                bf1[tm] = pk.s;
            }
            for (int tg = 0; tg < 4; ++tg) {
                short4v a2 = *(const short4v*)(&sW2T[(lq + 16 * tg) * WPAD + quad * 4 + 16 * th]);
                for (int tm = 0; tm < 4; ++tm)
                    acc2[tg][tm] = __builtin_amdgcn_mfma_f32_16x16x16bf16_1k(a2, bf1[tm], acc2[tg][tm], 0, 0, 0);
            }
        }
        float4v acc3[4];
        for (int tm = 0; tm < 4; ++tm) { acc3[tm][0] = b30; acc3[tm][1] = b31; acc3[tm][2] = 0.f; acc3[tm][3] = 0.f; }
        for (int tg = 0; tg < 4; ++tg) {
            short4v a3 = (short4v)0;
            if (lq < 2) a3 = *(const short4v*)(&sW3T[lq * 64 + quad * 4 + 16 * tg]);
            for (int tm = 0; tm < 4; ++tm) {
                union { short4v s; unsigned int u[2]; } pk;
                pk.u[0] = cvt_relu(acc2[tg][tm][0], acc2[tg][tm][1]);
                pk.u[1] = cvt_relu(acc2[tg][tm][2], acc2[tg][tm][3]);
                acc3[tm] = __builtin_amdgcn_mfma_f32_16x16x16bf16_1k(a3, pk.s, acc3[tm], 0, 0, 0);
            }
        }
        if (quad == 0) {
            for (int tm = 0; tm < 4; ++tm) {
                const size_t r = (size_t)(rowbase + 16 * tm + lq);
                out[r * 64 + net] = fminf(fmaxf(acc3[tm][0], -5.f), 5.f);
                out[(size_t)BATCH * 64 + r * 64 + net] = acc3[tm][1];
            }
        }
    }
}

extern "C" void kernel_launch(void* const* d_in, const int* in_sizes, int n_in,
                              void* d_out, int out_size, void* d_ws, size_t ws_size,
                              hipStream_t stream) {
    const float* x  = (const float*)d_in[0];
    const float* w0 = (const float*)d_in[1];
    const float* b0 = (const float*)d_in[2];
    const float* v0 = (const float*)d_in[3];
    const float* c0 = (const float*)d_in[4];
    const float* W1 = (const float*)d_in[5];
    const float* B1 = (const float*)d_in[6];
    const float* W2 = (const float*)d_in[7];
    const float* B2 = (const float*)d_in[8];
    const float* W3 = (const float*)d_in[9];
    const float* B3 = (const float*)d_in[10];
    float* out = (float*)d_out;
    char* ws = (char*)d_ws;

    const dim3 blk(256);

    if (ws_size >= FR_SIZE + XBF_SIZE) {
        char* xbf = ws + FR_SIZE;
        setup_kernel<<<dim3(63 + 256), blk, 0, stream>>>(x, W1, W2, W3, B1, B2, ws, xbf);
        arnet_main4<true><<<dim3(1024), blk, 0, stream>>>(
            x, xbf, ws, w0, b0, v0, c0, B3, out);
    } else if (ws_size >= FR_SIZE) {
        setup_kernel<<<dim3(63), blk, 0, stream>>>(x, W1, W2, W3, B1, B2, ws, nullptr);
        arnet_main4<false><<<dim3(1024), blk, 0, stream>>>(
            x, nullptr, ws, w0, b0, v0, c0, B3, out);
    } else {
        arnet_fallback<<<dim3(64 * 32), blk, 0, stream>>>(
            x, w0, b0, v0, c0, W1, B1, W2, B2, W3, B3, out);
    }
}

// Round 8
// 102.156 us; speedup vs baseline: 1.9447x; 1.9447x over previous
//
#include <hip/hip_runtime.h>
#include <hip/hip_bf16.h>

#define BATCH 16384

typedef __attribute__((ext_vector_type(8))) short short8;
typedef __attribute__((ext_vector_type(4))) short short4v;
typedef __attribute__((ext_vector_type(2))) short sshort2;
typedef __attribute__((ext_vector_type(8))) unsigned short ushort8;
typedef __attribute__((ext_vector_type(4))) unsigned short ushort4v;
typedef __attribute__((ext_vector_type(4))) float float4v;

// ---- d_ws layout (bytes) ----
// Per-net CONTIGUOUS frag block (staged whole into LDS):
//   [A1: [th:4][lane:64][32B] = 8192 | A2: [p:2][tg:4][lane:64][16B] = 8192 |
//    A3: [p:2][lane:64][16B] = 2048 | B1: 64 f32 = 256 | B2: 64 f32 = 256]
// A2/A3 laid out for 16x16x32 MFMA with k-slot permutation
//   phi(quad,j) = 32p + ((j>=4)?16:0) + 4*quad + (j&3)
// matching the L1/L2 output fragment (h = 16*th + 4*quad + i) so a th-step PAIR
// feeds one K=32 MFMA with zero shuffles (R5-verified: 112 -> 72 MFMA issues).
#define FR_STRIDE  18944u
#define FR_SIZE    (63u * FR_STRIDE)      // 1193472
#define OFF_A2     8192u
#define OFF_A3     16384u
#define OFF_B1     18432u
#define OFF_B2     18688u
#define XBF_SIZE   2097152u     // x as bf16 [16384][64]
#define FR_ELEMS   1184         // FR_STRIDE / 16

__device__ __forceinline__ unsigned int packbf2(float a, float b) {
#if __has_builtin(__builtin_amdgcn_cvt_pk_bf16_f32)
    typedef __attribute__((ext_vector_type(2))) __bf16 bf2_t;
    union { bf2_t h; unsigned int u; } v;
    v.h = __builtin_amdgcn_cvt_pk_bf16_f32(a, b);
    return v.u;
#else
    union { __hip_bfloat162 h; unsigned int u; } v;
    v.h = __float22bfloat162_rn(make_float2(a, b));
    return v.u;
#endif
}
// packed relu on two bf16 halves: i16 max with 0 (valid: bf16 neg <=> i16 neg; no NaNs here)
__device__ __forceinline__ unsigned int relu_pk(unsigned int u) {
#if __has_builtin(__builtin_elementwise_max)
    union { sshort2 s; unsigned int w; } v; v.w = u;
    v.s = __builtin_elementwise_max(v.s, (sshort2)0);
    return v.w;
#else
    unsigned int lo = (u & 0x8000u) ? 0u : (u & 0xFFFFu);
    unsigned int hi = (u & 0x80000000u) ? 0u : (u & 0xFFFF0000u);
    return lo | hi;
#endif
}
__device__ __forceinline__ unsigned int cvt_relu(float a, float b) {
    return relu_pk(packbf2(a, b));
}
__device__ __forceinline__ unsigned short f2bf(float a) {
    union { __hip_bfloat16 h; unsigned short u; } v;
    v.h = __float2bfloat16(a);
    return v.u;
}

// async 16B global -> LDS DMA (wave-uniform LDS base + lane*16 by construction)
__device__ __forceinline__ void gl_lds16(const char* gsrc, char* ldst) {
    __builtin_amdgcn_global_load_lds(
        (const __attribute__((address_space(1))) unsigned int*)gsrc,
        (__attribute__((address_space(3))) unsigned int*)ldst,
        16, 0, 0);
}

// ---------------- setup: fused weight-fragment prep (blocks 0..62) + x cvt (blocks 63..318) ----------------
__global__ __launch_bounds__(256) void setup_kernel(
    const float* __restrict__ x,
    const float* __restrict__ W1,  // [63,64,64] [d][h]
    const float* __restrict__ W2,  // [63,64,64] [h][g]
    const float* __restrict__ W3,  // [63,64,2]  [g][o]
    const float* __restrict__ B1,  // [63,64]
    const float* __restrict__ B2,  // [63,64]
    char* __restrict__ frag,
    char* __restrict__ xbf)        // may be null when grid==63
{
    const int b = blockIdx.x;
    const int t = threadIdx.x;

    if (b >= 63) {
        const int idx = (b - 63) * 256 + t;          // 0..65535, 16 floats each
        const float* xp = x + (size_t)idx * 16;
        char* dst = xbf + (size_t)idx * 32;
        #pragma unroll
        for (int h = 0; h < 2; ++h) {
            float4v f0 = *(const float4v*)(xp + h * 8);
            float4v f1 = *(const float4v*)(xp + h * 8 + 4);
            union { ushort8 s; unsigned int u[4]; } p;
            p.u[0] = packbf2(f0[0], f0[1]);
            p.u[1] = packbf2(f0[2], f0[3]);
            p.u[2] = packbf2(f1[0], f1[1]);
            p.u[3] = packbf2(f1[2], f1[3]);
            *(ushort8*)(dst + h * 16) = p.s;
        }
        return;
    }

    __shared__ float sW1[4096];   // 16 KB
    __shared__ float sW2[4096];   // 16 KB

    const int kn   = b;
    const int net  = kn + 1;
    const int lane = t & 63;
    const int grp  = t >> 6;       // th (A1) / p (A3)
    const int lq   = lane & 15;
    const int quad = lane >> 4;

    // coalesced stage: 4 float4 per thread per matrix
    {
        const float4v* s1 = (const float4v*)(W1 + kn * 4096);
        const float4v* s2 = (const float4v*)(W2 + kn * 4096);
        #pragma unroll
        for (int i = 0; i < 4; ++i) {
            ((float4v*)sW1)[i * 256 + t] = s1[i * 256 + t];
            ((float4v*)sW2)[i * 256 + t] = s2[i * 256 + t];
        }
    }
    __syncthreads();

    char* base = frag + (size_t)kn * FR_STRIDE;

    // A1: A[m=h=lq+16*th][k=d=quad*8+j (a10) / +32 (a11)], masked d < net
    {
        const int h = lq + 16 * grp;
        ushort8 a10, a11;
        #pragma unroll
        for (int j = 0; j < 8; ++j) {
            const int d0 = quad * 8 + j;
            const int d1 = d0 + 32;
            a10[j] = (d0 < net) ? f2bf(sW1[d0 * 64 + h]) : (unsigned short)0;
            a11[j] = (d1 < net) ? f2bf(sW1[d1 * 64 + h]) : (unsigned short)0;
        }
        char* dst = base + grp * 2048 + lane * 32;
        *(ushort8*)(dst)      = a10;
        *(ushort8*)(dst + 16) = a11;
    }

    // A2 (16x16x32): A[m=g=lq+16*tg][k-slot (quad,j)] with h = phi(quad,j)
    // pair p covers h in [32p, 32p+32)
    {
        const int g = lq + 16 * grp;   // grp doubles as tg here
        #pragma unroll
        for (int p = 0; p < 2; ++p) {
            ushort8 v;
            #pragma unroll
            for (int j = 0; j < 8; ++j) {
                const int h = 32 * p + ((j & 4) << 2) + 4 * quad + (j & 3);
                v[j] = f2bf(sW2[h * 64 + g]);
            }
            *(ushort8*)(base + OFF_A2 + p * 4096 + grp * 1024 + lane * 16) = v;
        }
    }

    // A3 (16x16x32): A[m=o=lq (0/1)][k-slot (quad,j)] with g = phi(quad,j); rows >= 2 zero
    if (grp < 2) {
        const int p = grp;
        ushort8 v;
        #pragma unroll
        for (int j = 0; j < 8; ++j) {
            const int gg = 32 * p + ((j & 4) << 2) + 4 * quad + (j & 3);
            v[j] = (lq < 2) ? f2bf(W3[kn * 128 + gg * 2 + lq]) : (unsigned short)0;
        }
        *(ushort8*)(base + OFF_A3 + p * 1024 + lane * 16) = v;
    }

    // B1/B2 raw f32 copies
    if (t < 64) {
        *(float*)(base + OFF_B1 + t * 4) = B1[kn * 64 + t];
        *(float*)(base + OFF_B2 + t * 4) = B2[kn * 64 + t];
    }
}

// ---------------- main: grid 768 = 64 chunks x 12 UNEVEN net-groups (R6-verified 103us) ----------------
// R8: R7's direct-store experiment REVERTED — counters showed 34x write amplification
// (WRITE_SIZE 8.2MB -> 270MB, FETCH 181MB): per-column 4B stores share 64B lines
// across 16 blocks; L2 does NOT merge them. sOut LDS tile + contiguous stores is
// load-bearing. New delta: masked-L1 skip — W1 cols >= net are zero, so for
// net <= 32 the a11 half-K is a zero matrix; skip its 16 MFMAs (wave-uniform
// branch, bit-exact: f32 + 0.0). ~11% off the MFMA-pipe floor, and it speeds
// the 6-net groups (nets 0..35) that set the makespan.
template <bool XBF>
__global__ __launch_bounds__(256, 3) void arnet_main4(
    const float* __restrict__ x,
    const char* __restrict__ xbf,
    const char* __restrict__ frag,
    const float* __restrict__ w0, const float* __restrict__ b0,
    const float* __restrict__ v0, const float* __restrict__ c0,
    const float* __restrict__ B3,
    float* __restrict__ out)
{
    const int bi    = blockIdx.x;        // 0..767
    const int chunk = bi & 63;           // 256-row chunk
    const int gi    = bi >> 6;           // 0..11
    const int start = (gi < 8) ? 6 * gi : 48 + 4 * (gi - 8);
    const int cnt   = (gi < 8) ? 6 : 4;
    const int t     = threadIdx.x;

    const int lane = t & 63;
    const int w    = t >> 6;
    const int lq   = lane & 15;
    const int quad = lane >> 4;

    __shared__ __align__(16) char sFrag[2][FR_STRIDE];   // 37888 B double-buffer
    __shared__ float sOut[2][256][7];                    // 14336 B (pad 7: banks spread)

    const int rowbase = chunk * 256 + w * 64;

    // ---- load x fragments ONCE (64 rows/wave), reuse for all nets of the group ----
    short8 xf[4][2];
    #pragma unroll
    for (int tm = 0; tm < 4; ++tm) {
        if (XBF) {
            const char* base = xbf + (size_t)(rowbase + 16 * tm + lq) * 128 + quad * 16;
            xf[tm][0] = *(const short8*)(base);
            xf[tm][1] = *(const short8*)(base + 64);
        } else {
            const float* xr = x + (size_t)(rowbase + 16 * tm + lq) * 64 + quad * 8;
            #pragma unroll
            for (int half = 0; half < 2; ++half) {
                float4v f0 = *(const float4v*)(xr + 32 * half);
                float4v f1 = *(const float4v*)(xr + 32 * half + 4);
                union { short8 s; unsigned int u[4]; } p;
                p.u[0] = packbf2(f0[0], f0[1]);
                p.u[1] = packbf2(f0[2], f0[3]);
                p.u[2] = packbf2(f1[0], f1[1]);
                p.u[3] = packbf2(f1[2], f1[3]);
                xf[tm][half] = p.s;
            }
        }
    }

    // ---- async stage of one net's frag block into LDS ----
    auto stage = [&](int net_, char* dstb) {
        const char* src = frag + (size_t)(net_ - 1) * FR_STRIDE;
        #pragma unroll
        for (int i = 0; i < 5; ++i) {
            const int e = i * 256 + t;
            if (e < FR_ELEMS)
                gl_lds16(src + e * 16, dstb + e * 16);
        }
    };

    const int first = (start == 0) ? 1 : 0;  // idx of first MFMA net in this group
    stage(start + first, sFrag[first & 1]);
    __syncthreads();                          // drain vmcnt -> first buffer ready

    #pragma unroll 1
    for (int idx = 0; idx < cnt; ++idx) {
        const int net = start + idx;

        // prefetch next net while computing this one (skips the pre-staged first)
        if (idx + 1 < cnt && idx + 1 > first)
            stage(start + idx + 1, sFrag[(idx + 1) & 1]);

        if (net == 0) {
            // constant network: uniform scalar; each thread fills col 0 of its row
            float s = 0.f, tr = 0.f;
            #pragma unroll 8
            for (int j = 0; j < 64; ++j) {
                float h = fmaxf(w0[j] + b0[j], 0.f);
                s  += h * v0[2 * j];
                tr += h * v0[2 * j + 1];
            }
            s += c0[0];
            tr += c0[1];
            s = fminf(fmaxf(s, -5.f), 5.f);
            sOut[0][t][0] = s;
            sOut[1][t][0] = tr;
            __syncthreads();                  // iteration barrier (drains prefetch)
            continue;
        }

        const int kn = net - 1;
        const char* sf  = sFrag[idx & 1];
        const char* pA1 = sf + lane * 32;
        const char* pA2 = sf + OFF_A2 + lane * 16;
        const char* pA3 = sf + OFF_A3 + lane * 16;
        const float* bB1 = (const float*)(sf + OFF_B1);
        const float* bB2 = (const float*)(sf + OFF_B2);

        // ---- inner body, tm=4, paired th-steps -> K=32 L2/L3 ----
        // masked-L1 skip: for net <= 32, W1 rows d in [32,64) are all zero ->
        // a11 is a zero matrix -> its MFMA adds +0.0 exactly; skip (uniform branch).
        const bool hiK = (net > 32);
        float4v acc2[4][4];
        #pragma unroll
        for (int p = 0; p < 2; ++p) {
            unsigned int pk[2][2][4];   // [sub-th][dword][tm], fully unrolled static idx
            #pragma unroll
            for (int s = 0; s < 2; ++s) {
                const int th = 2 * p + s;
                short8 a10 = *(const short8*)(pA1 + th * 2048);
                float4v bias1 = *(const float4v*)(bB1 + quad * 4 + 16 * th);
                if (hiK) {
                    short8 a11 = *(const short8*)(pA1 + th * 2048 + 16);
                    #pragma unroll
                    for (int tm = 0; tm < 4; ++tm) {
                        float4v acc1;
                        acc1 = __builtin_amdgcn_mfma_f32_16x16x32_bf16(a10, xf[tm][0], bias1, 0, 0, 0);
                        acc1 = __builtin_amdgcn_mfma_f32_16x16x32_bf16(a11, xf[tm][1], acc1, 0, 0, 0);
                        pk[s][0][tm] = cvt_relu(acc1[0], acc1[1]);
                        pk[s][1][tm] = cvt_relu(acc1[2], acc1[3]);
                    }
                } else {
                    #pragma unroll
                    for (int tm = 0; tm < 4; ++tm) {
                        float4v acc1;
                        acc1 = __builtin_amdgcn_mfma_f32_16x16x32_bf16(a10, xf[tm][0], bias1, 0, 0, 0);
                        pk[s][0][tm] = cvt_relu(acc1[0], acc1[1]);
                        pk[s][1][tm] = cvt_relu(acc1[2], acc1[3]);
                    }
                }
            }
            #pragma unroll
            for (int tg = 0; tg < 4; ++tg) {
                short8 a2 = *(const short8*)(pA2 + p * 4096 + tg * 1024);
                float4v bias2 = *(const float4v*)(bB2 + quad * 4 + 16 * tg);
                #pragma unroll
                for (int tm = 0; tm < 4; ++tm) {
                    union { short8 s8; unsigned int u[4]; } bb;
                    bb.u[0] = pk[0][0][tm]; bb.u[1] = pk[0][1][tm];
                    bb.u[2] = pk[1][0][tm]; bb.u[3] = pk[1][1][tm];
                    acc2[tg][tm] = __builtin_amdgcn_mfma_f32_16x16x32_bf16(
                        a2, bb.s8, (p == 0) ? bias2 : acc2[tg][tm], 0, 0, 0);
                }
            }
        }

        // ---- layer 3: paired tg-steps -> K=32 ----
        float4v c3v;
        c3v[0] = B3[kn * 2]; c3v[1] = B3[kn * 2 + 1]; c3v[2] = 0.f; c3v[3] = 0.f;
        float4v acc3[4];
        #pragma unroll
        for (int p = 0; p < 2; ++p) {
            short8 a3 = *(const short8*)(pA3 + p * 1024);
            #pragma unroll
            for (int tm = 0; tm < 4; ++tm) {
                union { short8 s8; unsigned int u[4]; } bb;
                bb.u[0] = cvt_relu(acc2[2 * p][tm][0],     acc2[2 * p][tm][1]);
                bb.u[1] = cvt_relu(acc2[2 * p][tm][2],     acc2[2 * p][tm][3]);
                bb.u[2] = cvt_relu(acc2[2 * p + 1][tm][0], acc2[2 * p + 1][tm][1]);
                bb.u[3] = cvt_relu(acc2[2 * p + 1][tm][2], acc2[2 * p + 1][tm][3]);
                acc3[tm] = __builtin_amdgcn_mfma_f32_16x16x32_bf16(
                    a3, bb.s8, (p == 0) ? c3v : acc3[tm], 0, 0, 0);
            }
        }

        // ---- epilogue -> LDS tile (col = idx) ----
        if (quad == 0) {
            #pragma unroll
            for (int tm = 0; tm < 4; ++tm) {
                const int lr = w * 64 + 16 * tm + lq;
                sOut[0][lr][idx] = fminf(fmaxf(acc3[tm][0], -5.f), 5.f);
                sOut[1][lr][idx] = acc3[tm][1];
            }
        }
        __syncthreads();                      // drains prefetch DMA + orders dbuf reuse
    }

    // ---- dense write-out: thread t = row; both outputs, cnt cols via float2 (8B-aligned: start,cnt even) ----
    {
        const int row = t;                       // 0..255
        const size_t grow = (size_t)chunk * 256 + row;
        #pragma unroll
        for (int o = 0; o < 2; ++o) {
            float* dst = out + ((size_t)o * BATCH + grow) * 64 + start;
            #pragma unroll
            for (int c = 0; c < 6; c += 2) {
                if (c < cnt) {
                    float2 v2;
                    v2.x = sOut[o][row][c];
                    v2.y = sOut[o][row][c + 1];
                    *(float2*)(dst + c) = v2;
                }
            }
        }
    }
}

// ---------------- fallback (verified): used only if ws_size < FR_SIZE ----------------
#define WPAD 72
__global__ __launch_bounds__(256) void arnet_fallback(
    const float* __restrict__ x, const float* __restrict__ w0, const float* __restrict__ b0,
    const float* __restrict__ v0, const float* __restrict__ c0,
    const float* __restrict__ W1, const float* __restrict__ B1,
    const float* __restrict__ W2, const float* __restrict__ B2,
    const float* __restrict__ W3, const float* __restrict__ B3,
    float* __restrict__ out)
{
    const int bi = blockIdx.x;
    const int net = bi >> 5;
    const int tile = bi & 31;
    const int t = threadIdx.x;
    if (net == 0) {
        float s = 0.f, tr = 0.f;
        for (int j = 0; j < 64; ++j) {
            float h = fmaxf(w0[j] + b0[j], 0.f);
            s += h * v0[2 * j]; tr += h * v0[2 * j + 1];
        }
        s += c0[0]; tr += c0[1];
        s = fminf(fmaxf(s, -5.f), 5.f);
        const size_t r0 = (size_t)tile * 512;
        out[(r0 + t) * 64] = s; out[(size_t)BATCH * 64 + (r0 + t) * 64] = tr;
        out[(r0 + 256 + t) * 64] = s; out[(size_t)BATCH * 64 + (r0 + 256 + t) * 64] = tr;
        return;
    }
    __shared__ unsigned short sW1T[64 * WPAD];
    __shared__ unsigned short sW2T[64 * WPAD];
    __shared__ unsigned short sW3T[2 * 64];
    __shared__ float sB1[64];
    __shared__ float sB2[64];
    const int kn = net - 1;
    {
        const int hb = (t & 15) * 4, jb = (t >> 4) * 4;
        const float* src1 = W1 + kn * 4096;
        const float* src2 = W2 + kn * 4096;
        float4v a[4], b[4];
        for (int jj = 0; jj < 4; ++jj) {
            a[jj] = *(const float4v*)(src1 + (jb + jj) * 64 + hb);
            if (jb + jj >= net) a[jj] = (float4v)0.f;
            b[jj] = *(const float4v*)(src2 + (jb + jj) * 64 + hb);
        }
        for (int hh = 0; hh < 4; ++hh) {
            ushort4v ra, rb;
            for (int jj = 0; jj < 4; ++jj) { ra[jj] = f2bf(a[jj][hh]); rb[jj] = f2bf(b[jj][hh]); }
            *(ushort4v*)(&sW1T[(hb + hh) * WPAD + jb]) = ra;
            *(ushort4v*)(&sW2T[(hb + hh) * WPAD + jb]) = rb;
        }
    }
    if (t < 64) {
        sW3T[t] = f2bf(W3[kn * 128 + t * 2]);
        sW3T[64 + t] = f2bf(W3[kn * 128 + t * 2 + 1]);
        sB1[t] = B1[kn * 64 + t];
        sB2[t] = B2[kn * 64 + t];
    }
    const float b30 = B3[kn * 2], b31 = B3[kn * 2 + 1];
    __syncthreads();
    const int lane = t & 63, w = t >> 6, lq = lane & 15, quad = lane >> 4;
    for (int pass = 0; pass < 2; ++pass) {
        const int rowbase = tile * 512 + pass * 256 + w * 64;
        short8 xf[4][2];
        for (int tm = 0; tm < 4; ++tm) {
            const float* xr = x + (size_t)(rowbase + 16 * tm + lq) * 64 + quad * 8;
            for (int half = 0; half < 2; ++half) {
                float4v f0 = *(const float4v*)(xr + 32 * half);
                float4v f1 = *(const float4v*)(xr + 32 * half + 4);
                union { short8 s; unsigned int u[4]; } p;
                p.u[0] = packbf2(f0[0], f0[1]); p.u[1] = packbf2(f0[2], f0[3]);
                p.u[2] = packbf2(f1[0], f1[1]); p.u[3] = packbf2(f1[2], f1[3]);
                xf[tm][half] = p.s;
            }
        }
        float4v acc2[4][4];
        for (int tg = 0; tg < 4; ++tg) {
            float4v bias2 = *(const float4v*)(&sB2[quad * 4 + 16 * tg]);
            for (int tm = 0; tm < 4; ++tm) acc2[tg][tm] = bias2;
        }
        for (int th = 0; th < 4; ++th) {
            float4v bias1 = *(const float4v*)(&sB1[quad * 4 + 16 * th]);
            short8 a10 = *(const short8*)(&sW1T[(lq + 16 * th) * WPAD + quad * 8]);
            short8 a11 = *(const short8*)(&sW1T[(lq + 16 * th) * WPAD + quad * 8 + 32]);
            float4v acc1[4];
            for (int tm = 0; tm < 4; ++tm) {
                acc1[tm] = bias1;
                acc1[tm] = __builtin_amdgcn_mfma_f32_16x16x32_bf16(a10, xf[tm][0], acc1[tm], 0, 0, 0);
                acc1[tm] = __builtin_amdgcn_mfma_f32_16x16x32_bf16(a11, xf[tm][1], acc1[tm], 0, 0, 0);
            }
            short4v bf1[4];
            for (int tm = 0; tm < 4; ++tm) {
                union { short4v s; unsigned int u[2]; } pk;
                pk.u[0] = cvt_relu(acc1[tm][0], acc1[tm][1]);
                pk.u[1] = cvt_relu(acc1[tm][2], acc1[tm][3]);
                bf1[tm] = pk.s;
            }
            for (int tg = 0; tg < 4; ++tg) {
                short4v a2 = *(const short4v*)(&sW2T[(lq + 16 * tg) * WPAD + quad * 4 + 16 * th]);
                for (int tm = 0; tm < 4; ++tm)
                    acc2[tg][tm] = __builtin_amdgcn_mfma_f32_16x16x16bf16_1k(a2, bf1[tm], acc2[tg][tm], 0, 0, 0);
            }
        }
        float4v acc3[4];
        for (int tm = 0; tm < 4; ++tm) { acc3[tm][0] = b30; acc3[tm][1] = b31; acc3[tm][2] = 0.f; acc3[tm][3] = 0.f; }
        for (int tg = 0; tg < 4; ++tg) {
            short4v a3 = (short4v)0;
            if (lq < 2) a3 = *(const short4v*)(&sW3T[lq * 64 + quad * 4 + 16 * tg]);
            for (int tm = 0; tm < 4; ++tm) {
                union { short4v s; unsigned int u[2]; } pk;
                pk.u[0] = cvt_relu(acc2[tg][tm][0], acc2[tg][tm][1]);
                pk.u[1] = cvt_relu(acc2[tg][tm][2], acc2[tg][tm][3]);
                acc3[tm] = __builtin_amdgcn_mfma_f32_16x16x16bf16_1k(a3, pk.s, acc3[tm], 0, 0, 0);
            }
        }
        if (quad == 0) {
            for (int tm = 0; tm < 4; ++tm) {
                const size_t r = (size_t)(rowbase + 16 * tm + lq);
                out[r * 64 + net] = fminf(fmaxf(acc3[tm][0], -5.f), 5.f);
                out[(size_t)BATCH * 64 + r * 64 + net] = acc3[tm][1];
            }
        }
    }
}

extern "C" void kernel_launch(void* const* d_in, const int* in_sizes, int n_in,
                              void* d_out, int out_size, void* d_ws, size_t ws_size,
                              hipStream_t stream) {
    const float* x  = (const float*)d_in[0];
    const float* w0 = (const float*)d_in[1];
    const float* b0 = (const float*)d_in[2];
    const float* v0 = (const float*)d_in[3];
    const float* c0 = (const float*)d_in[4];
    const float* W1 = (const float*)d_in[5];
    const float* B1 = (const float*)d_in[6];
    const float* W2 = (const float*)d_in[7];
    const float* B2 = (const float*)d_in[8];
    const float* W3 = (const float*)d_in[9];
    const float* B3 = (const float*)d_in[10];
    float* out = (float*)d_out;
    char* ws = (char*)d_ws;

    const dim3 blk(256);

    if (ws_size >= FR_SIZE + XBF_SIZE) {
        char* xbf = ws + FR_SIZE;
        setup_kernel<<<dim3(63 + 256), blk, 0, stream>>>(x, W1, W2, W3, B1, B2, ws, xbf);
        arnet_main4<true><<<dim3(768), blk, 0, stream>>>(
            x, xbf, ws, w0, b0, v0, c0, B3, out);
    } else if (ws_size >= FR_SIZE) {
        setup_kernel<<<dim3(63), blk, 0, stream>>>(x, W1, W2, W3, B1, B2, ws, nullptr);
        arnet_main4<false><<<dim3(768), blk, 0, stream>>>(
            x, nullptr, ws, w0, b0, v0, c0, B3, out);
    } else {
        arnet_fallback<<<dim3(64 * 32), blk, 0, stream>>>(
            x, w0, b0, v0, c0, W1, B1, W2, B2, W3, B3, out);
    }
}